// Round 3
// baseline (368.796 us; speedup 1.0000x reference)
//
#include <hip/hip_runtime.h>
#include <math.h>

namespace {
constexpr int B = 512, S = 64, K = 8, D = 16, NR = 64, NSTEPS = 100, NUNITS = 128;
}

// ---------------------------------------------------------------------------
// Diffusion alpha schedule: betas = sigmoid(linspace(-6,6,100))*(0.005-1e-5)+1e-5
// aprod = cumprod(1-betas); sa = sqrt(aprod), so = sqrt(1-aprod)
// ---------------------------------------------------------------------------
__global__ void k_sched(float* __restrict__ sa, float* __restrict__ so) {
    int i = threadIdx.x;
    if (i < NSTEPS) {
        float prod = 1.0f;
        for (int jj = 0; jj <= i; ++jj) {
            float x = -6.0f + (float)jj * (12.0f / 99.0f);
            float sig = 1.0f / (1.0f + expf(-x));
            float beta = sig * (0.005f - 1e-5f) + 1e-5f;
            prod *= (1.0f - beta);
        }
        sa[i] = sqrtf(prod);
        so[i] = sqrtf(1.0f - prod);
    }
}

// ---------------------------------------------------------------------------
// w[b][r] = mean_d( usr_emb[u[b]][d] * rel_emb[r][d] )
// ---------------------------------------------------------------------------
__global__ void k_userrel(const float* __restrict__ usr_emb,
                          const float* __restrict__ rel_emb,
                          const int* __restrict__ u,
                          float* __restrict__ w) {
    int b = blockIdx.x, r = threadIdx.x;   // 512 blocks x 64 threads
    const float* ur = usr_emb + (long)u[b] * D;
    const float* rr = rel_emb + r * D;
    float s = 0.f;
#pragma unroll
    for (int d = 0; d < D; ++d) s += ur[d] * rr[d];
    w[b * NR + r] = s * (1.0f / (float)D);
}

// ---------------------------------------------------------------------------
// R2: fission of the pointer-chase. One thread per p = (b,s): each lane owns
// a DISTINCT p, so every chain level is 64 independent cache lines per wave
// (vs 1-2 in the fused version). Writes e1s[p*8+k], r0s[p*8+k] coalesced.
// ---------------------------------------------------------------------------
__global__ __launch_bounds__(256) void k_prep(
    const int* __restrict__ click_seq,   // [B*S]
    const int* __restrict__ adj_ent,     // [NE, K]
    const int* __restrict__ adj_rel,     // [NE, K]
    int* __restrict__ e1s,               // [B*S*K]
    int* __restrict__ r0s)               // [B*S*K]
{
    int p = blockIdx.x * blockDim.x + threadIdx.x;   // 32768 threads
    int e0 = click_seq[p];
    const int4* ae = (const int4*)(adj_ent + (long)e0 * K);
    const int4* ar = (const int4*)(adj_rel + (long)e0 * K);
    int4 a0 = ae[0], a1 = ae[1];
    int4 b0 = ar[0], b1 = ar[1];
    int4* oe = (int4*)(e1s + (long)p * K);
    int4* orr = (int4*)(r0s + (long)p * K);
    oe[0] = a0; oe[1] = a1;
    orr[0] = b0; orr[1] = b1;
}

// ---------------------------------------------------------------------------
// KGCN: one 64-lane wave per (b,s) pair; 4 pairs per 256-thread block.
// Lane = (k,j): owns level-2 neighbor e2[k][j]. e1/r0 come precomputed from
// ws (L2/L3-warm coalesced reads), so the wide gathers issue immediately.
// ---------------------------------------------------------------------------
__global__ __launch_bounds__(256) void k_kgcn(
    const float* __restrict__ ent_emb,
    const float* __restrict__ w_tab,      // [B, NR]
    const int* __restrict__ click_seq,    // [B*S]
    const int* __restrict__ adj_ent,      // [NE, K]
    const int* __restrict__ adj_rel,      // [NE, K]
    const int* __restrict__ e1s,          // [B*S*K] precomputed
    const int* __restrict__ r0s,          // [B*S*K] precomputed
    const float* __restrict__ agg_W,      // [D, D]
    const float* __restrict__ agg_b,      // [D]
    float* __restrict__ item)             // [B*S, D]
{
    __shared__ float wb[NR];
    __shared__ float Ws[D][D + 1];
    __shared__ float bs[D];
    __shared__ float Ms[4][K][D + 1];
    __shared__ float h1s[4][K][D + 1];
    __shared__ float h0s[4][D];

    const int tid = threadIdx.x;
    const int pg = tid >> 6;            // pair-in-block 0..3
    const int lane = tid & 63;
    const int p = blockIdx.x * 4 + pg;  // pair id = b*S + s
    const int b = blockIdx.x >> 4;      // 4 pairs/block, 64 pairs/b -> same b per block

    const int k = lane >> 3, j = lane & 7;

    // ---- index loads first (ws reads are warm; wide gathers issue asap)
    const int e0 = click_seq[p];
    const int e1k = e1s[(long)p * K + k];
    const int r0k = r0s[(long)p * K + k];
    const int e2kj = adj_ent[(long)e1k * K + j];
    const int r1kj = adj_rel[(long)e1k * K + j];

    // ---- LDS staging (independent of the loads above)
    Ws[tid >> 4][tid & 15] = agg_W[tid];
    if (tid < NR) wb[tid] = w_tab[b * NR + tid];
    if (tid < D) bs[tid] = agg_b[tid];
    __syncthreads();

    // ---- hop-1 softmax over j (within 8-lane groups; xor masks 1,2,4 stay in-group)
    float s1 = wb[r1kj];
    float m1 = s1;
    m1 = fmaxf(m1, __shfl_xor(m1, 1));
    m1 = fmaxf(m1, __shfl_xor(m1, 2));
    m1 = fmaxf(m1, __shfl_xor(m1, 4));
    float ex = expf(s1 - m1);
    float den = ex;
    den += __shfl_xor(den, 1);
    den += __shfl_xor(den, 2);
    den += __shfl_xor(den, 4);
    float p1 = ex / den;

    // ---- gather q2 row (64 B), weight by p1, butterfly-reduce over j
    float agg[D];
    {
        const float4* q2p = (const float4*)(ent_emb + (long)e2kj * D);
        float4 a0 = q2p[0], a1 = q2p[1], a2 = q2p[2], a3 = q2p[3];
        agg[0] = p1 * a0.x;  agg[1] = p1 * a0.y;  agg[2] = p1 * a0.z;  agg[3] = p1 * a0.w;
        agg[4] = p1 * a1.x;  agg[5] = p1 * a1.y;  agg[6] = p1 * a1.z;  agg[7] = p1 * a1.w;
        agg[8] = p1 * a2.x;  agg[9] = p1 * a2.y;  agg[10] = p1 * a2.z; agg[11] = p1 * a2.w;
        agg[12] = p1 * a3.x; agg[13] = p1 * a3.y; agg[14] = p1 * a3.z; agg[15] = p1 * a3.w;
    }
#pragma unroll
    for (int m = 1; m <= 4; m <<= 1)
#pragma unroll
        for (int d = 0; d < D; ++d) agg[d] += __shfl_xor(agg[d], m);

    // ---- q1 row (broadcast across the 8 lanes of the group)
    float q1[D];
    {
        const float4* q1p = (const float4*)(ent_emb + (long)e1k * D);
        float4 a0 = q1p[0], a1 = q1p[1], a2 = q1p[2], a3 = q1p[3];
        q1[0] = a0.x;  q1[1] = a0.y;  q1[2] = a0.z;  q1[3] = a0.w;
        q1[4] = a1.x;  q1[5] = a1.y;  q1[6] = a1.z;  q1[7] = a1.w;
        q1[8] = a2.x;  q1[9] = a2.y;  q1[10] = a2.z; q1[11] = a2.w;
        q1[12] = a3.x; q1[13] = a3.y; q1[14] = a3.z; q1[15] = a3.w;
    }
    // M[k] = self(q1) + neigh_agg  (lane j writes elements 2j, 2j+1)
    Ms[pg][k][2 * j]     = q1[2 * j]     + agg[2 * j];
    Ms[pg][k][2 * j + 1] = q1[2 * j + 1] + agg[2 * j + 1];
    __syncthreads();

    // ---- h1[k] = sigmoid(M[k] @ W + b); 128 outputs over 64 lanes (2 each)
#pragma unroll
    for (int o = lane; o < 128; o += 64) {
        int ko = o >> 4, dd = o & 15;
        float acc = bs[dd];
#pragma unroll
        for (int din = 0; din < D; ++din) acc += Ms[pg][ko][din] * Ws[din][dd];
        h1s[pg][ko][dd] = 1.0f / (1.0f + expf(-acc));
    }

    // ---- hop-0 softmax over k (xor masks 8,16,32 keep j fixed)
    float s0 = wb[r0k];
    float m0 = s0;
    m0 = fmaxf(m0, __shfl_xor(m0, 8));
    m0 = fmaxf(m0, __shfl_xor(m0, 16));
    m0 = fmaxf(m0, __shfl_xor(m0, 32));
    float e0x = expf(s0 - m0);
    float d0 = e0x;
    d0 += __shfl_xor(d0, 8);
    d0 += __shfl_xor(d0, 16);
    d0 += __shfl_xor(d0, 32);
    float p0 = e0x / d0;

    // ---- agg0 = sum_k p0_k * q1[k]  (butterfly over k)
    float ag0[D];
#pragma unroll
    for (int d = 0; d < D; ++d) ag0[d] = p0 * q1[d];
#pragma unroll
    for (int m = 8; m <= 32; m <<= 1)
#pragma unroll
        for (int d = 0; d < D; ++d) ag0[d] += __shfl_xor(ag0[d], m);

    // ---- q0 row; h0 = sigmoid((q0 + agg0) @ W + b) (each lane computes dout = lane&15)
    float q0v[D];
    {
        const float4* q0p = (const float4*)(ent_emb + (long)e0 * D);
        float4 a0 = q0p[0], a1 = q0p[1], a2 = q0p[2], a3 = q0p[3];
        q0v[0] = a0.x;  q0v[1] = a0.y;  q0v[2] = a0.z;  q0v[3] = a0.w;
        q0v[4] = a1.x;  q0v[5] = a1.y;  q0v[6] = a1.z;  q0v[7] = a1.w;
        q0v[8] = a2.x;  q0v[9] = a2.y;  q0v[10] = a2.z; q0v[11] = a2.w;
        q0v[12] = a3.x; q0v[13] = a3.y; q0v[14] = a3.z; q0v[15] = a3.w;
    }
    const int ddl = lane & 15;
    float acc0 = bs[ddl];
#pragma unroll
    for (int din = 0; din < D; ++din) acc0 += (q0v[din] + ag0[din]) * Ws[din][ddl];
    float h0v = 1.0f / (1.0f + expf(-acc0));
    if (lane < 16) h0s[pg][lane] = h0v;
    __syncthreads();   // h1s + h0s now visible

    // ---- iteration 1 (tanh): agg1 = sum_k p0_k * h1[k]; same p0 (rel/user unchanged)
    float ag1[D];
#pragma unroll
    for (int d = 0; d < D; ++d) ag1[d] = p0 * h1s[pg][k][d];
#pragma unroll
    for (int m = 8; m <= 32; m <<= 1)
#pragma unroll
        for (int d = 0; d < D; ++d) ag1[d] += __shfl_xor(ag1[d], m);

    float acc1 = bs[ddl];
#pragma unroll
    for (int din = 0; din < D; ++din) acc1 += (h0s[pg][din] + ag1[din]) * Ws[din][ddl];
    float fin = tanhf(acc1);
    if (lane < 16) item[(long)p * D + lane] = fmaxf(fin, 0.0f);
}

// ---------------------------------------------------------------------------
// Per-b fusion head: sum/max over S, fc1 (32->64), fc2 (64->16), dot ent_emb[v]
// ---------------------------------------------------------------------------
__global__ __launch_bounds__(64) void k_fuse(
    const float* __restrict__ item,     // [B*S, D]
    const float* __restrict__ fc1_W,    // [32, 64]
    const float* __restrict__ fc1_b,    // [64]
    const float* __restrict__ fc2_W,    // [64, 16]
    const float* __restrict__ fc2_b,    // [16]
    const float* __restrict__ ent_emb,
    const int* __restrict__ v,
    float* __restrict__ out)            // [B, 17]
{
    __shared__ float sm[S][D + 1];
    __shared__ float fus[2 * D];
    __shared__ float hid[64];
    __shared__ float feat_s[D];

    int b = blockIdx.x, t = threadIdx.x;   // 64 threads, t = s index
    const float4* ip = (const float4*)(item + ((long)b * S + t) * D);
    float4 r0 = ip[0], r1 = ip[1], r2 = ip[2], r3 = ip[3];
    sm[t][0] = r0.x;  sm[t][1] = r0.y;  sm[t][2] = r0.z;  sm[t][3] = r0.w;
    sm[t][4] = r1.x;  sm[t][5] = r1.y;  sm[t][6] = r1.z;  sm[t][7] = r1.w;
    sm[t][8] = r2.x;  sm[t][9] = r2.y;  sm[t][10] = r2.z; sm[t][11] = r2.w;
    sm[t][12] = r3.x; sm[t][13] = r3.y; sm[t][14] = r3.z; sm[t][15] = r3.w;
    __syncthreads();

    if (t < D) {
        float sv = 0.0f, mv = -1e30f;
        for (int ss = 0; ss < S; ++ss) {
            float x = sm[ss][t];
            sv += x;
            mv = fmaxf(mv, x);
        }
        fus[t] = fmaxf(sv, 0.0f);
        fus[D + t] = fmaxf(mv, 0.0f);
    }
    __syncthreads();

    // fc1: hid[t] = relu(fus @ fc1_W[:,t] + b)
    float a = fc1_b[t];
#pragma unroll
    for (int i = 0; i < 2 * D; ++i) a += fus[i] * fc1_W[i * 64 + t];
    hid[t] = fmaxf(a, 0.0f);
    __syncthreads();

    if (t < D) {
        float f = fc2_b[t];
#pragma unroll
        for (int i = 0; i < 64; ++i) f += hid[i] * fc2_W[i * D + t];
        feat_s[t] = fmaxf(f, 0.0f);
    }
    __syncthreads();

    if (t < D) {
        float g = feat_s[t] * ent_emb[(long)v[b] * D + t];
        g += __shfl_xor(g, 1);
        g += __shfl_xor(g, 2);
        g += __shfl_xor(g, 4);
        g += __shfl_xor(g, 8);
        if (t == 0) out[(long)b * 17] = 1.0f / (1.0f + expf(-g));
    }
}

// ---------------------------------------------------------------------------
// Diffusion MLP: x0 -> 128 -> 128 -> 128 -> 16, one block (128 thr) per sample
// ---------------------------------------------------------------------------
__global__ __launch_bounds__(128) void k_diff(
    const float* __restrict__ usr_emb, const float* __restrict__ noise_e,
    const int* __restrict__ u, const int* __restrict__ t_arr,
    const float* __restrict__ W1, const float* __restrict__ b1,
    const float* __restrict__ W2, const float* __restrict__ b2,
    const float* __restrict__ W3, const float* __restrict__ b3,
    const float* __restrict__ W4, const float* __restrict__ b4,
    const float* __restrict__ se1, const float* __restrict__ se2,
    const float* __restrict__ se3,
    const float* __restrict__ sa, const float* __restrict__ so,
    float* __restrict__ out)   // [B, 17]
{
    __shared__ float x0[D];
    __shared__ float ha[NUNITS];
    __shared__ float hb[NUNITS];

    int b = blockIdx.x, t = threadIdx.x;
    int ts = t_arr[b];
    if (t < D) {
        x0[t] = usr_emb[(long)u[b] * D + t] * sa[ts] + noise_e[(long)b * D + t] * so[ts];
    }
    __syncthreads();

    // layer 1
    float a = b1[t] + se1[(long)ts * NUNITS + t];
#pragma unroll
    for (int i = 0; i < D; ++i) a += x0[i] * W1[i * NUNITS + t];
    ha[t] = fmaxf(a, 0.0f);
    __syncthreads();

    // layer 2
    a = b2[t] + se2[(long)ts * NUNITS + t];
    for (int i = 0; i < NUNITS; ++i) a += ha[i] * W2[i * NUNITS + t];
    hb[t] = fmaxf(a, 0.0f);
    __syncthreads();

    // layer 3
    a = b3[t] + se3[(long)ts * NUNITS + t];
    for (int i = 0; i < NUNITS; ++i) a += hb[i] * W3[i * NUNITS + t];
    __syncthreads();
    ha[t] = fmaxf(a, 0.0f);
    __syncthreads();

    // layer 4: 16 outputs
    if (t < D) {
        float acc = b4[t];
        for (int i = 0; i < NUNITS; ++i) acc += ha[i] * W4[i * D + t];
        out[(long)b * 17 + 1 + t] = acc;
    }
}

// ---------------------------------------------------------------------------
extern "C" void kernel_launch(void* const* d_in, const int* in_sizes, int n_in,
                              void* d_out, int out_size, void* d_ws, size_t ws_size,
                              hipStream_t stream) {
    const float* usr_emb = (const float*)d_in[0];
    const float* ent_emb = (const float*)d_in[1];
    const float* rel_emb = (const float*)d_in[2];
    const float* agg_W   = (const float*)d_in[3];
    const float* agg_b   = (const float*)d_in[4];
    const float* fc1_W   = (const float*)d_in[5];
    const float* fc1_b   = (const float*)d_in[6];
    const float* fc2_W   = (const float*)d_in[7];
    const float* fc2_b   = (const float*)d_in[8];
    const float* mlp_W1  = (const float*)d_in[9];
    const float* mlp_b1  = (const float*)d_in[10];
    const float* mlp_W2  = (const float*)d_in[11];
    const float* mlp_b2  = (const float*)d_in[12];
    const float* mlp_W3  = (const float*)d_in[13];
    const float* mlp_b3  = (const float*)d_in[14];
    const float* mlp_W4  = (const float*)d_in[15];
    const float* mlp_b4  = (const float*)d_in[16];
    const float* se1     = (const float*)d_in[17];
    const float* se2     = (const float*)d_in[18];
    const float* se3     = (const float*)d_in[19];
    const float* noise_e = (const float*)d_in[20];
    const int* u         = (const int*)d_in[21];
    const int* v         = (const int*)d_in[22];
    const int* click_seq = (const int*)d_in[23];
    const int* adj_ent   = (const int*)d_in[24];
    const int* adj_rel   = (const int*)d_in[25];
    const int* t         = (const int*)d_in[26];
    float* out = (float*)d_out;

    float* ws = (float*)d_ws;
    float* w_tab = ws;                   // B*NR floats
    float* sa    = w_tab + B * NR;       // 128 floats (NSTEPS used)
    float* so    = sa + 128;             // 128 floats
    float* item  = so + 128;             // B*S*D floats
    int*   e1s   = (int*)(item + B * S * D);   // B*S*K ints
    int*   r0s   = e1s + B * S * K;            // B*S*K ints

    k_sched<<<1, 128, 0, stream>>>(sa, so);
    k_userrel<<<B, NR, 0, stream>>>(usr_emb, rel_emb, u, w_tab);
    k_prep<<<(B * S) / 256, 256, 0, stream>>>(click_seq, adj_ent, adj_rel, e1s, r0s);
    k_kgcn<<<(B * S) / 4, 256, 0, stream>>>(ent_emb, w_tab, click_seq, adj_ent, adj_rel,
                                            e1s, r0s, agg_W, agg_b, item);
    k_fuse<<<B, 64, 0, stream>>>(item, fc1_W, fc1_b, fc2_W, fc2_b, ent_emb, v, out);
    k_diff<<<B, NUNITS, 0, stream>>>(usr_emb, noise_e, u, t, mlp_W1, mlp_b1, mlp_W2, mlp_b2,
                                     mlp_W3, mlp_b3, mlp_W4, mlp_b4, se1, se2, se3, sa, so, out);
}

// Round 4
// 339.654 us; speedup vs baseline: 1.0858x; 1.0858x over previous
//
#include <hip/hip_runtime.h>
#include <math.h>

namespace {
constexpr int B = 512, S = 64, K = 8, D = 16, NR = 64, NSTEPS = 100, NUNITS = 128;
}

// ---------------------------------------------------------------------------
// Fused prep: (t<64) w_tab[b][r] user-relation scores; (64<=t<128) hop-1
// index prefetch e1s/r0s; (b==0, t in [128,228)) diffusion alpha schedule.
// All three are independent lane-parallel jobs — no barriers.
// ---------------------------------------------------------------------------
__global__ __launch_bounds__(256) void k_prep_all(
    const float* __restrict__ usr_emb, const float* __restrict__ rel_emb,
    const int* __restrict__ u, const int* __restrict__ click_seq,
    const int* __restrict__ adj_ent, const int* __restrict__ adj_rel,
    float* __restrict__ w_tab, int* __restrict__ e1s, int* __restrict__ r0s,
    float* __restrict__ sa, float* __restrict__ so)
{
    int b = blockIdx.x, t = threadIdx.x;
    if (t < 64) {
        const float* ur = usr_emb + (long)u[b] * D;
        const float* rr = rel_emb + t * D;
        float s = 0.f;
#pragma unroll
        for (int d = 0; d < D; ++d) s += ur[d] * rr[d];
        w_tab[b * NR + t] = s * (1.0f / 16.0f);
    } else if (t < 128) {
        int p = b * S + (t - 64);
        int e0 = click_seq[p];
        const int4* ae = (const int4*)(adj_ent + (long)e0 * K);
        const int4* ar = (const int4*)(adj_rel + (long)e0 * K);
        int4 a0 = ae[0], a1 = ae[1], b0 = ar[0], b1 = ar[1];
        int4* oe = (int4*)(e1s + (long)p * K);
        int4* orr = (int4*)(r0s + (long)p * K);
        oe[0] = a0; oe[1] = a1;
        orr[0] = b0; orr[1] = b1;
    } else if (b == 0 && (t - 128) < NSTEPS) {
        int i = t - 128;
        float prod = 1.0f;
        for (int jj = 0; jj <= i; ++jj) {
            float x = -6.0f + (float)jj * (12.0f / 99.0f);
            float sig = 1.0f / (1.0f + expf(-x));
            prod *= (1.0f - (sig * (0.005f - 1e-5f) + 1e-5f));
        }
        sa[i] = sqrtf(prod);
        so[i] = sqrtf(1.0f - prod);
    }
}

// ---------------------------------------------------------------------------
// KGCN: ONE WAVE = ONE PAIR (64-thread blocks). All LDS is wave-private, so
// the __syncthreads() are intra-wave (near-free) and waves never wait on
// other pairs' cache misses (R3's 4-pair blocks lock-stepped on the slowest
// wave's gathers). Reductions use reduce-scatter halving: each stage keeps
// the half this lane will eventually own (bit-reversed dim mapping), 42 ops
// instead of 96 per 16-float tree, landing exactly the 2 dims written out.
// ---------------------------------------------------------------------------
__global__ __launch_bounds__(64) void k_kgcn(
    const float* __restrict__ ent_emb,
    const float* __restrict__ w_tab,      // [B, NR]
    const int* __restrict__ click_seq,    // [B*S]
    const int* __restrict__ adj_ent,      // [NE, K]
    const int* __restrict__ adj_rel,      // [NE, K]
    const int* __restrict__ e1s,          // [B*S*K] precomputed
    const int* __restrict__ r0s,          // [B*S*K] precomputed
    const float* __restrict__ agg_W,      // [D, D]
    const float* __restrict__ agg_b,      // [D]
    float* __restrict__ item)             // [B*S, D]
{
    __shared__ float wb[NR];
    __shared__ float Ws[D][D + 1];
    __shared__ float bs[D];
    __shared__ float Ms[K][D + 1];
    __shared__ float h1s[K][D + 1];
    __shared__ float h0s[D];
    __shared__ float A0s[D];
    __shared__ float M1s[D];
    __shared__ float p0s[K];

    const int lane = threadIdx.x;
    const int p = blockIdx.x;           // pair id = b*S + s
    const int b = p >> 6;
    const int k = lane >> 3, j = lane & 7;

    // ---- index loads (e1s/r0s warm from k_prep_all), then the wide gathers
    const int e0 = click_seq[p];
    const int e1k = e1s[(long)p * K + k];
    const int r0k = r0s[(long)p * K + k];
    const int e2kj = adj_ent[(long)e1k * K + j];
    const int r1kj = adj_rel[(long)e1k * K + j];

    // ---- LDS staging (64 lanes: 4 agg_W vals each via float4)
    {
        const float4 wv = ((const float4*)agg_W)[lane];     // agg_W[4l..4l+3]
        int row = lane >> 2, col = (lane & 3) * 4;
        Ws[row][col] = wv.x; Ws[row][col + 1] = wv.y;
        Ws[row][col + 2] = wv.z; Ws[row][col + 3] = wv.w;
        wb[lane] = w_tab[b * NR + lane];
        if (lane < D) bs[lane] = agg_b[lane];
    }
    __syncthreads();

    // ---- hop-1 softmax over j (masks 1,2,4 stay inside the 8-lane j-group)
    float s1 = wb[r1kj];
    float m1 = s1;
    m1 = fmaxf(m1, __shfl_xor(m1, 1));
    m1 = fmaxf(m1, __shfl_xor(m1, 2));
    m1 = fmaxf(m1, __shfl_xor(m1, 4));
    float ex = expf(s1 - m1);
    float den = ex;
    den += __shfl_xor(den, 1);
    den += __shfl_xor(den, 2);
    den += __shfl_xor(den, 4);
    float p1 = ex / den;

    // ---- gather rows: q2 (own), q1 (group-shared), q0 (wave-shared)
    float q2r[D], q1r[D], q0r[D];
    {
        const float4* q2p = (const float4*)(ent_emb + (long)e2kj * D);
        float4 a0 = q2p[0], a1 = q2p[1], a2 = q2p[2], a3 = q2p[3];
        q2r[0]=a0.x; q2r[1]=a0.y; q2r[2]=a0.z; q2r[3]=a0.w;
        q2r[4]=a1.x; q2r[5]=a1.y; q2r[6]=a1.z; q2r[7]=a1.w;
        q2r[8]=a2.x; q2r[9]=a2.y; q2r[10]=a2.z; q2r[11]=a2.w;
        q2r[12]=a3.x; q2r[13]=a3.y; q2r[14]=a3.z; q2r[15]=a3.w;
    }
    {
        const float4* q1p = (const float4*)(ent_emb + (long)e1k * D);
        float4 a0 = q1p[0], a1 = q1p[1], a2 = q1p[2], a3 = q1p[3];
        q1r[0]=a0.x; q1r[1]=a0.y; q1r[2]=a0.z; q1r[3]=a0.w;
        q1r[4]=a1.x; q1r[5]=a1.y; q1r[6]=a1.z; q1r[7]=a1.w;
        q1r[8]=a2.x; q1r[9]=a2.y; q1r[10]=a2.z; q1r[11]=a2.w;
        q1r[12]=a3.x; q1r[13]=a3.y; q1r[14]=a3.z; q1r[15]=a3.w;
    }
    {
        const float4* q0p = (const float4*)(ent_emb + (long)e0 * D);
        float4 a0 = q0p[0], a1 = q0p[1], a2 = q0p[2], a3 = q0p[3];
        q0r[0]=a0.x; q0r[1]=a0.y; q0r[2]=a0.z; q0r[3]=a0.w;
        q0r[4]=a1.x; q0r[5]=a1.y; q0r[6]=a1.z; q0r[7]=a1.w;
        q0r[8]=a2.x; q0r[9]=a2.y; q0r[10]=a2.z; q0r[11]=a2.w;
        q0r[12]=a3.x; q0r[13]=a3.y; q0r[14]=a3.z; q0r[15]=a3.w;
    }

    // ---- hop-1 j-reduction (reduce-scatter, masks 1,2,4). Lane keeps the
    // half it will own; final 2 dims at dbase = 8(j&1)+4(j>>1&1)+2(j>>2&1).
    {
        float cur[16];
#pragma unroll
        for (int d = 0; d < 16; ++d) cur[d] = p1 * q2r[d];
        const bool b0 = (lane & 1), b1 = (lane & 2), b2 = (lane & 4);
        float n8[8];
#pragma unroll
        for (int d = 0; d < 8; ++d) {
            float snd = b0 ? cur[d] : cur[d + 8];
            float kp  = b0 ? cur[d + 8] : cur[d];
            n8[d] = kp + __shfl_xor(snd, 1);
        }
        float n4[4];
#pragma unroll
        for (int d = 0; d < 4; ++d) {
            float snd = b1 ? n8[d] : n8[d + 4];
            float kp  = b1 ? n8[d + 4] : n8[d];
            n4[d] = kp + __shfl_xor(snd, 2);
        }
        float a0 = (b2 ? n4[2] : n4[0]) + __shfl_xor(b2 ? n4[0] : n4[2], 4);
        float a1 = (b2 ? n4[3] : n4[1]) + __shfl_xor(b2 ? n4[1] : n4[3], 4);
        const int dbase = (b0 ? 8 : 0) + (b1 ? 4 : 0) + (b2 ? 2 : 0);
        Ms[k][dbase]     = q1r[dbase]     + a0;   // self + neigh_agg
        Ms[k][dbase + 1] = q1r[dbase + 1] + a1;
    }

    // ---- hop-0 softmax over k (masks 8,16,32 keep j fixed)
    float s0 = wb[r0k];
    float m0 = s0;
    m0 = fmaxf(m0, __shfl_xor(m0, 8));
    m0 = fmaxf(m0, __shfl_xor(m0, 16));
    m0 = fmaxf(m0, __shfl_xor(m0, 32));
    float e0x = expf(s0 - m0);
    float d0 = e0x;
    d0 += __shfl_xor(d0, 8);
    d0 += __shfl_xor(d0, 16);
    d0 += __shfl_xor(d0, 32);
    float p0 = e0x / d0;
    if (j == 0) p0s[k] = p0;

    // ---- ag0 = sum_k p0_k * q1[k]: reduce-scatter over k (masks 8,16,32);
    // identical values across j, so j==0 lanes deposit the 16 dims in A0s.
    {
        float cur[16];
#pragma unroll
        for (int d = 0; d < 16; ++d) cur[d] = p0 * q1r[d];
        const bool c0 = (lane & 8), c1 = (lane & 16), c2 = (lane & 32);
        float n8[8];
#pragma unroll
        for (int d = 0; d < 8; ++d) {
            float snd = c0 ? cur[d] : cur[d + 8];
            float kp  = c0 ? cur[d + 8] : cur[d];
            n8[d] = kp + __shfl_xor(snd, 8);
        }
        float n4[4];
#pragma unroll
        for (int d = 0; d < 4; ++d) {
            float snd = c1 ? n8[d] : n8[d + 4];
            float kp  = c1 ? n8[d + 4] : n8[d];
            n4[d] = kp + __shfl_xor(snd, 16);
        }
        float a0 = (c2 ? n4[2] : n4[0]) + __shfl_xor(c2 ? n4[0] : n4[2], 32);
        float a1 = (c2 ? n4[3] : n4[1]) + __shfl_xor(c2 ? n4[1] : n4[3], 32);
        const int dbase = (c0 ? 8 : 0) + (c1 ? 4 : 0) + (c2 ? 2 : 0);
        if (j == 0) { A0s[dbase] = a0; A0s[dbase + 1] = a1; }
    }
    __syncthreads();   // Ms, A0s, p0s ready (intra-wave: near-free)

    // ---- h1[k] = sigmoid(M[k] @ W + b): 128 outputs over 64 lanes (2 each)
#pragma unroll
    for (int o = lane; o < 128; o += 64) {
        int ko = o >> 4, dd = o & 15;
        float acc = bs[dd];
#pragma unroll
        for (int din = 0; din < D; ++din) acc += Ms[ko][din] * Ws[din][dd];
        h1s[ko][dd] = 1.0f / (1.0f + expf(-acc));
    }

    // ---- h0 = sigmoid((q0 + ag0) @ W + b)
    const int ddl = lane & 15;
    {
        float acc = bs[ddl];
#pragma unroll
        for (int din = 0; din < D; ++din)
            acc += (q0r[din] + A0s[din]) * Ws[din][ddl];
        if (lane < D) h0s[lane] = 1.0f / (1.0f + expf(-acc));
    }
    __syncthreads();   // h1s, h0s ready

    // ---- iteration 1 input vector: M1 = h0 + sum_k p0_k * h1[k]
    if (lane < D) {
        float m = h0s[lane];
#pragma unroll
        for (int kk = 0; kk < K; ++kk) m += p0s[kk] * h1s[kk][lane];
        M1s[lane] = m;
    }
    __syncthreads();   // M1s ready

    // ---- final: relu(tanh(M1 @ W + b))
    {
        float acc = bs[ddl];
#pragma unroll
        for (int din = 0; din < D; ++din) acc += M1s[din] * Ws[din][ddl];
        if (lane < D) item[(long)p * D + lane] = fmaxf(tanhf(acc), 0.0f);
    }
}

// ---------------------------------------------------------------------------
// Fused tail (one block per b, 128 threads): diffusion MLP (all threads) +
// fusion head (t<64). Independent outputs; barriers reached by all threads.
// ---------------------------------------------------------------------------
__global__ __launch_bounds__(128) void k_tail(
    const float* __restrict__ item,     // [B*S, D]
    const float* __restrict__ fc1_W, const float* __restrict__ fc1_b,
    const float* __restrict__ fc2_W, const float* __restrict__ fc2_b,
    const float* __restrict__ ent_emb, const int* __restrict__ v,
    const float* __restrict__ usr_emb, const float* __restrict__ noise_e,
    const int* __restrict__ u, const int* __restrict__ t_arr,
    const float* __restrict__ W1, const float* __restrict__ b1,
    const float* __restrict__ W2, const float* __restrict__ b2,
    const float* __restrict__ W3, const float* __restrict__ b3,
    const float* __restrict__ W4, const float* __restrict__ b4,
    const float* __restrict__ se1, const float* __restrict__ se2,
    const float* __restrict__ se3,
    const float* __restrict__ sa, const float* __restrict__ so,
    float* __restrict__ out)            // [B, 17]
{
    __shared__ float x0[D];
    __shared__ float ha[NUNITS];
    __shared__ float hb[NUNITS];
    __shared__ float sm[S][D + 1];
    __shared__ float fus[2 * D];
    __shared__ float hid[64];
    __shared__ float feat_s[D];

    int b = blockIdx.x, t = threadIdx.x;
    int ts = t_arr[b];

    // ======== diffusion MLP ========
    if (t < D)
        x0[t] = usr_emb[(long)u[b] * D + t] * sa[ts] + noise_e[(long)b * D + t] * so[ts];
    __syncthreads();

    float a = b1[t] + se1[(long)ts * NUNITS + t];
#pragma unroll
    for (int i = 0; i < D; ++i) a += x0[i] * W1[i * NUNITS + t];
    ha[t] = fmaxf(a, 0.0f);
    __syncthreads();

    a = b2[t] + se2[(long)ts * NUNITS + t];
    for (int i = 0; i < NUNITS; ++i) a += ha[i] * W2[i * NUNITS + t];
    hb[t] = fmaxf(a, 0.0f);
    __syncthreads();

    a = b3[t] + se3[(long)ts * NUNITS + t];
    for (int i = 0; i < NUNITS; ++i) a += hb[i] * W3[i * NUNITS + t];
    __syncthreads();
    ha[t] = fmaxf(a, 0.0f);
    __syncthreads();

    if (t < D) {
        float acc = b4[t];
        for (int i = 0; i < NUNITS; ++i) acc += ha[i] * W4[i * D + t];
        out[(long)b * 17 + 1 + t] = acc;
    }

    // ======== fusion head (threads < 64 active; barriers hit by all) ========
    if (t < 64) {
        const float4* ip = (const float4*)(item + ((long)b * S + t) * D);
        float4 r0 = ip[0], r1 = ip[1], r2 = ip[2], r3 = ip[3];
        sm[t][0]=r0.x;  sm[t][1]=r0.y;  sm[t][2]=r0.z;  sm[t][3]=r0.w;
        sm[t][4]=r1.x;  sm[t][5]=r1.y;  sm[t][6]=r1.z;  sm[t][7]=r1.w;
        sm[t][8]=r2.x;  sm[t][9]=r2.y;  sm[t][10]=r2.z; sm[t][11]=r2.w;
        sm[t][12]=r3.x; sm[t][13]=r3.y; sm[t][14]=r3.z; sm[t][15]=r3.w;
    }
    __syncthreads();

    if (t < D) {
        float sv = 0.0f, mv = -1e30f;
        for (int ss = 0; ss < S; ++ss) {
            float x = sm[ss][t];
            sv += x;
            mv = fmaxf(mv, x);
        }
        fus[t] = fmaxf(sv, 0.0f);
        fus[D + t] = fmaxf(mv, 0.0f);
    }
    __syncthreads();

    if (t < 64) {
        float acc = fc1_b[t];
#pragma unroll
        for (int i = 0; i < 2 * D; ++i) acc += fus[i] * fc1_W[i * 64 + t];
        hid[t] = fmaxf(acc, 0.0f);
    }
    __syncthreads();

    if (t < D) {
        float f = fc2_b[t];
#pragma unroll
        for (int i = 0; i < 64; ++i) f += hid[i] * fc2_W[i * D + t];
        feat_s[t] = fmaxf(f, 0.0f);
    }
    __syncthreads();

    if (t < D) {
        float g = feat_s[t] * ent_emb[(long)v[b] * D + t];
        g += __shfl_xor(g, 1);
        g += __shfl_xor(g, 2);
        g += __shfl_xor(g, 4);
        g += __shfl_xor(g, 8);
        if (t == 0) out[(long)b * 17] = 1.0f / (1.0f + expf(-g));
    }
}

// ---------------------------------------------------------------------------
extern "C" void kernel_launch(void* const* d_in, const int* in_sizes, int n_in,
                              void* d_out, int out_size, void* d_ws, size_t ws_size,
                              hipStream_t stream) {
    const float* usr_emb = (const float*)d_in[0];
    const float* ent_emb = (const float*)d_in[1];
    const float* rel_emb = (const float*)d_in[2];
    const float* agg_W   = (const float*)d_in[3];
    const float* agg_b   = (const float*)d_in[4];
    const float* fc1_W   = (const float*)d_in[5];
    const float* fc1_b   = (const float*)d_in[6];
    const float* fc2_W   = (const float*)d_in[7];
    const float* fc2_b   = (const float*)d_in[8];
    const float* mlp_W1  = (const float*)d_in[9];
    const float* mlp_b1  = (const float*)d_in[10];
    const float* mlp_W2  = (const float*)d_in[11];
    const float* mlp_b2  = (const float*)d_in[12];
    const float* mlp_W3  = (const float*)d_in[13];
    const float* mlp_b3  = (const float*)d_in[14];
    const float* mlp_W4  = (const float*)d_in[15];
    const float* mlp_b4  = (const float*)d_in[16];
    const float* se1     = (const float*)d_in[17];
    const float* se2     = (const float*)d_in[18];
    const float* se3     = (const float*)d_in[19];
    const float* noise_e = (const float*)d_in[20];
    const int* u         = (const int*)d_in[21];
    const int* v         = (const int*)d_in[22];
    const int* click_seq = (const int*)d_in[23];
    const int* adj_ent   = (const int*)d_in[24];
    const int* adj_rel   = (const int*)d_in[25];
    const int* t         = (const int*)d_in[26];
    float* out = (float*)d_out;

    float* ws = (float*)d_ws;
    float* w_tab = ws;                         // B*NR floats
    float* sa    = w_tab + B * NR;             // 128 floats (NSTEPS used)
    float* so    = sa + 128;                   // 128 floats
    float* item  = so + 128;                   // B*S*D floats
    int*   e1s   = (int*)(item + B * S * D);   // B*S*K ints
    int*   r0s   = e1s + B * S * K;            // B*S*K ints

    k_prep_all<<<B, 256, 0, stream>>>(usr_emb, rel_emb, u, click_seq, adj_ent, adj_rel,
                                      w_tab, e1s, r0s, sa, so);
    k_kgcn<<<B * S, 64, 0, stream>>>(ent_emb, w_tab, click_seq, adj_ent, adj_rel,
                                     e1s, r0s, agg_W, agg_b, item);
    k_tail<<<B, 128, 0, stream>>>(item, fc1_W, fc1_b, fc2_W, fc2_b, ent_emb, v,
                                  usr_emb, noise_e, u, t, mlp_W1, mlp_b1, mlp_W2, mlp_b2,
                                  mlp_W3, mlp_b3, mlp_W4, mlp_b4, se1, se2, se3, sa, so, out);
}

// Round 5
// 335.701 us; speedup vs baseline: 1.0986x; 1.0118x over previous
//
#include <hip/hip_runtime.h>
#include <math.h>

namespace {
constexpr int B = 512, S = 64, K = 8, D = 16, NR = 64, NSTEPS = 100, NUNITS = 128;
}

// Intra-wave LDS fence: same-wave DS ops complete in order; this waits for
// all outstanding LDS ops and stops the compiler reordering LDS accesses
// across it. Replaces __syncthreads() for wave-private LDS (no vmcnt drain,
// no cross-wave coupling).
#define WAVE_LDS_FENCE() __asm__ volatile("s_waitcnt lgkmcnt(0)" ::: "memory")

// ---------------------------------------------------------------------------
// Fused prep: (t<64) w_tab[b][r] user-relation scores; (64<=t<128) hop-1
// index prefetch e1s/r0s; (b==0, t in [128,228)) diffusion alpha schedule.
// ---------------------------------------------------------------------------
__global__ __launch_bounds__(256) void k_prep_all(
    const float* __restrict__ usr_emb, const float* __restrict__ rel_emb,
    const int* __restrict__ u, const int* __restrict__ click_seq,
    const int* __restrict__ adj_ent, const int* __restrict__ adj_rel,
    float* __restrict__ w_tab, int* __restrict__ e1s, int* __restrict__ r0s,
    float* __restrict__ sa, float* __restrict__ so)
{
    int b = blockIdx.x, t = threadIdx.x;
    if (t < 64) {
        const float* ur = usr_emb + (long)u[b] * D;
        const float* rr = rel_emb + t * D;
        float s = 0.f;
#pragma unroll
        for (int d = 0; d < D; ++d) s += ur[d] * rr[d];
        w_tab[b * NR + t] = s * (1.0f / 16.0f);
    } else if (t < 128) {
        int p = b * S + (t - 64);
        int e0 = click_seq[p];
        const int4* ae = (const int4*)(adj_ent + (long)e0 * K);
        const int4* ar = (const int4*)(adj_rel + (long)e0 * K);
        int4 a0 = ae[0], a1 = ae[1], b0 = ar[0], b1 = ar[1];
        int4* oe = (int4*)(e1s + (long)p * K);
        int4* orr = (int4*)(r0s + (long)p * K);
        oe[0] = a0; oe[1] = a1;
        orr[0] = b0; orr[1] = b1;
    } else if (b == 0 && (t - 128) < NSTEPS) {
        int i = t - 128;
        float prod = 1.0f;
        for (int jj = 0; jj <= i; ++jj) {
            float x = -6.0f + (float)jj * (12.0f / 99.0f);
            float sig = 1.0f / (1.0f + expf(-x));
            prod *= (1.0f - (sig * (0.005f - 1e-5f) + 1e-5f));
        }
        sa[i] = sqrtf(prod);
        so[i] = sqrtf(1.0f - prod);
    }
}

// ---------------------------------------------------------------------------
// KGCN R5: 256-thread blocks carrying 4 WAVE-PRIVATE pairs, ZERO block
// barriers. R4's 64-thread blocks hit the ~24 workgroup-slot/CU cap
// (OccupancyPercent 75%); 4 waves/block reach 32 waves/CU while keeping
// waves fully decoupled (each wave owns its own LDS slab; fences are
// intra-wave lgkmcnt waits, which don't drain vmcnt or couple waves).
// ---------------------------------------------------------------------------
__global__ __launch_bounds__(256) void k_kgcn(
    const float* __restrict__ ent_emb,
    const float* __restrict__ w_tab,      // [B, NR]
    const int* __restrict__ click_seq,    // [B*S]
    const int* __restrict__ adj_ent,      // [NE, K]
    const int* __restrict__ adj_rel,      // [NE, K]
    const int* __restrict__ e1s,          // [B*S*K] precomputed
    const int* __restrict__ r0s,          // [B*S*K] precomputed
    const float* __restrict__ agg_W,      // [D, D]
    const float* __restrict__ agg_b,      // [D]
    float* __restrict__ item)             // [B*S, D]
{
    __shared__ float wb[4][NR];
    __shared__ float Ws[4][D][D + 1];
    __shared__ float bs[4][D];
    __shared__ float Ms[4][K][D + 1];
    __shared__ float h1s[4][K][D + 1];
    __shared__ float h0s[4][D];
    __shared__ float A0s[4][D];
    __shared__ float M1s[4][D];
    __shared__ float p0s[4][K];

    const int tid = threadIdx.x;
    const int w = tid >> 6;             // wave in block, 0..3
    const int lane = tid & 63;
    const int p = blockIdx.x * 4 + w;   // pair id = b*S + s (64%4==0 -> same b math ok)
    const int b = p >> 6;
    const int k = lane >> 3, j = lane & 7;

    // ---- index loads (e1s/r0s warm from k_prep_all), then the wide gathers
    const int e0 = click_seq[p];
    const int e1k = e1s[(long)p * K + k];
    const int r0k = r0s[(long)p * K + k];
    const int e2kj = adj_ent[(long)e1k * K + j];
    const int r1kj = adj_rel[(long)e1k * K + j];

    // ---- per-wave LDS staging (wave-private slab; no cross-wave sharing)
    {
        const float4 wv = ((const float4*)agg_W)[lane];     // agg_W[4l..4l+3]
        int row = lane >> 2, col = (lane & 3) * 4;
        Ws[w][row][col] = wv.x; Ws[w][row][col + 1] = wv.y;
        Ws[w][row][col + 2] = wv.z; Ws[w][row][col + 3] = wv.w;
        wb[w][lane] = w_tab[b * NR + lane];
        if (lane < D) bs[w][lane] = agg_b[lane];
    }
    WAVE_LDS_FENCE();   // wb/Ws/bs visible to this wave

    // ---- hop-1 softmax over j (masks 1,2,4 stay inside the 8-lane j-group)
    float s1 = wb[w][r1kj];
    float m1 = s1;
    m1 = fmaxf(m1, __shfl_xor(m1, 1));
    m1 = fmaxf(m1, __shfl_xor(m1, 2));
    m1 = fmaxf(m1, __shfl_xor(m1, 4));
    float ex = expf(s1 - m1);
    float den = ex;
    den += __shfl_xor(den, 1);
    den += __shfl_xor(den, 2);
    den += __shfl_xor(den, 4);
    float p1 = ex / den;

    // ---- gather rows: q2 (own), q1 (group-shared), q0 (wave-shared)
    float q2r[D], q1r[D], q0r[D];
    {
        const float4* q2p = (const float4*)(ent_emb + (long)e2kj * D);
        float4 a0 = q2p[0], a1 = q2p[1], a2 = q2p[2], a3 = q2p[3];
        q2r[0]=a0.x; q2r[1]=a0.y; q2r[2]=a0.z; q2r[3]=a0.w;
        q2r[4]=a1.x; q2r[5]=a1.y; q2r[6]=a1.z; q2r[7]=a1.w;
        q2r[8]=a2.x; q2r[9]=a2.y; q2r[10]=a2.z; q2r[11]=a2.w;
        q2r[12]=a3.x; q2r[13]=a3.y; q2r[14]=a3.z; q2r[15]=a3.w;
    }
    {
        const float4* q1p = (const float4*)(ent_emb + (long)e1k * D);
        float4 a0 = q1p[0], a1 = q1p[1], a2 = q1p[2], a3 = q1p[3];
        q1r[0]=a0.x; q1r[1]=a0.y; q1r[2]=a0.z; q1r[3]=a0.w;
        q1r[4]=a1.x; q1r[5]=a1.y; q1r[6]=a1.z; q1r[7]=a1.w;
        q1r[8]=a2.x; q1r[9]=a2.y; q1r[10]=a2.z; q1r[11]=a2.w;
        q1r[12]=a3.x; q1r[13]=a3.y; q1r[14]=a3.z; q1r[15]=a3.w;
    }
    {
        const float4* q0p = (const float4*)(ent_emb + (long)e0 * D);
        float4 a0 = q0p[0], a1 = q0p[1], a2 = q0p[2], a3 = q0p[3];
        q0r[0]=a0.x; q0r[1]=a0.y; q0r[2]=a0.z; q0r[3]=a0.w;
        q0r[4]=a1.x; q0r[5]=a1.y; q0r[6]=a1.z; q0r[7]=a1.w;
        q0r[8]=a2.x; q0r[9]=a2.y; q0r[10]=a2.z; q0r[11]=a2.w;
        q0r[12]=a3.x; q0r[13]=a3.y; q0r[14]=a3.z; q0r[15]=a3.w;
    }

    // ---- hop-1 j-reduction (reduce-scatter, masks 1,2,4). Lane keeps the
    // half it will own; final 2 dims at dbase = 8(j&1)+4(j>>1&1)+2(j>>2&1).
    {
        float cur[16];
#pragma unroll
        for (int d = 0; d < 16; ++d) cur[d] = p1 * q2r[d];
        const bool b0 = (lane & 1), b1 = (lane & 2), b2 = (lane & 4);
        float n8[8];
#pragma unroll
        for (int d = 0; d < 8; ++d) {
            float snd = b0 ? cur[d] : cur[d + 8];
            float kp  = b0 ? cur[d + 8] : cur[d];
            n8[d] = kp + __shfl_xor(snd, 1);
        }
        float n4[4];
#pragma unroll
        for (int d = 0; d < 4; ++d) {
            float snd = b1 ? n8[d] : n8[d + 4];
            float kp  = b1 ? n8[d + 4] : n8[d];
            n4[d] = kp + __shfl_xor(snd, 2);
        }
        float a0 = (b2 ? n4[2] : n4[0]) + __shfl_xor(b2 ? n4[0] : n4[2], 4);
        float a1 = (b2 ? n4[3] : n4[1]) + __shfl_xor(b2 ? n4[1] : n4[3], 4);
        const int dbase = (b0 ? 8 : 0) + (b1 ? 4 : 0) + (b2 ? 2 : 0);
        Ms[w][k][dbase]     = q1r[dbase]     + a0;   // self + neigh_agg
        Ms[w][k][dbase + 1] = q1r[dbase + 1] + a1;
    }

    // ---- hop-0 softmax over k (masks 8,16,32 keep j fixed)
    float s0 = wb[w][r0k];
    float m0 = s0;
    m0 = fmaxf(m0, __shfl_xor(m0, 8));
    m0 = fmaxf(m0, __shfl_xor(m0, 16));
    m0 = fmaxf(m0, __shfl_xor(m0, 32));
    float e0x = expf(s0 - m0);
    float d0 = e0x;
    d0 += __shfl_xor(d0, 8);
    d0 += __shfl_xor(d0, 16);
    d0 += __shfl_xor(d0, 32);
    float p0 = e0x / d0;
    if (j == 0) p0s[w][k] = p0;

    // ---- ag0 = sum_k p0_k * q1[k]: reduce-scatter over k (masks 8,16,32);
    // identical values across j, so j==0 lanes deposit the 16 dims in A0s.
    {
        float cur[16];
#pragma unroll
        for (int d = 0; d < 16; ++d) cur[d] = p0 * q1r[d];
        const bool c0 = (lane & 8), c1 = (lane & 16), c2 = (lane & 32);
        float n8[8];
#pragma unroll
        for (int d = 0; d < 8; ++d) {
            float snd = c0 ? cur[d] : cur[d + 8];
            float kp  = c0 ? cur[d + 8] : cur[d];
            n8[d] = kp + __shfl_xor(snd, 8);
        }
        float n4[4];
#pragma unroll
        for (int d = 0; d < 4; ++d) {
            float snd = c1 ? n8[d] : n8[d + 4];
            float kp  = c1 ? n8[d + 4] : n8[d];
            n4[d] = kp + __shfl_xor(snd, 16);
        }
        float a0 = (c2 ? n4[2] : n4[0]) + __shfl_xor(c2 ? n4[0] : n4[2], 32);
        float a1 = (c2 ? n4[3] : n4[1]) + __shfl_xor(c2 ? n4[1] : n4[3], 32);
        const int dbase = (c0 ? 8 : 0) + (c1 ? 4 : 0) + (c2 ? 2 : 0);
        if (j == 0) { A0s[w][dbase] = a0; A0s[w][dbase + 1] = a1; }
    }
    WAVE_LDS_FENCE();   // Ms, A0s, p0s ready

    // ---- h1[k] = sigmoid(M[k] @ W + b): 128 outputs over 64 lanes (2 each)
#pragma unroll
    for (int o = lane; o < 128; o += 64) {
        int ko = o >> 4, dd = o & 15;
        float acc = bs[w][dd];
#pragma unroll
        for (int din = 0; din < D; ++din) acc += Ms[w][ko][din] * Ws[w][din][dd];
        h1s[w][ko][dd] = 1.0f / (1.0f + expf(-acc));
    }

    // ---- h0 = sigmoid((q0 + ag0) @ W + b)
    const int ddl = lane & 15;
    {
        float acc = bs[w][ddl];
#pragma unroll
        for (int din = 0; din < D; ++din)
            acc += (q0r[din] + A0s[w][din]) * Ws[w][din][ddl];
        if (lane < D) h0s[w][lane] = 1.0f / (1.0f + expf(-acc));
    }
    WAVE_LDS_FENCE();   // h1s, h0s ready

    // ---- iteration 1 input vector: M1 = h0 + sum_k p0_k * h1[k]
    if (lane < D) {
        float m = h0s[w][lane];
#pragma unroll
        for (int kk = 0; kk < K; ++kk) m += p0s[w][kk] * h1s[w][kk][lane];
        M1s[w][lane] = m;
    }
    WAVE_LDS_FENCE();   // M1s ready

    // ---- final: relu(tanh(M1 @ W + b))
    {
        float acc = bs[w][ddl];
#pragma unroll
        for (int din = 0; din < D; ++din) acc += M1s[w][din] * Ws[w][din][ddl];
        if (lane < D) item[(long)p * D + lane] = fmaxf(tanhf(acc), 0.0f);
    }
}

// ---------------------------------------------------------------------------
// Fused tail (one block per b, 128 threads): diffusion MLP (all threads) +
// fusion head (t<64). Independent outputs; barriers reached by all threads.
// ---------------------------------------------------------------------------
__global__ __launch_bounds__(128) void k_tail(
    const float* __restrict__ item,     // [B*S, D]
    const float* __restrict__ fc1_W, const float* __restrict__ fc1_b,
    const float* __restrict__ fc2_W, const float* __restrict__ fc2_b,
    const float* __restrict__ ent_emb, const int* __restrict__ v,
    const float* __restrict__ usr_emb, const float* __restrict__ noise_e,
    const int* __restrict__ u, const int* __restrict__ t_arr,
    const float* __restrict__ W1, const float* __restrict__ b1,
    const float* __restrict__ W2, const float* __restrict__ b2,
    const float* __restrict__ W3, const float* __restrict__ b3,
    const float* __restrict__ W4, const float* __restrict__ b4,
    const float* __restrict__ se1, const float* __restrict__ se2,
    const float* __restrict__ se3,
    const float* __restrict__ sa, const float* __restrict__ so,
    float* __restrict__ out)            // [B, 17]
{
    __shared__ float x0[D];
    __shared__ float ha[NUNITS];
    __shared__ float hb[NUNITS];
    __shared__ float sm[S][D + 1];
    __shared__ float fus[2 * D];
    __shared__ float hid[64];
    __shared__ float feat_s[D];

    int b = blockIdx.x, t = threadIdx.x;
    int ts = t_arr[b];

    // ======== diffusion MLP ========
    if (t < D)
        x0[t] = usr_emb[(long)u[b] * D + t] * sa[ts] + noise_e[(long)b * D + t] * so[ts];
    __syncthreads();

    float a = b1[t] + se1[(long)ts * NUNITS + t];
#pragma unroll
    for (int i = 0; i < D; ++i) a += x0[i] * W1[i * NUNITS + t];
    ha[t] = fmaxf(a, 0.0f);
    __syncthreads();

    a = b2[t] + se2[(long)ts * NUNITS + t];
    for (int i = 0; i < NUNITS; ++i) a += ha[i] * W2[i * NUNITS + t];
    hb[t] = fmaxf(a, 0.0f);
    __syncthreads();

    a = b3[t] + se3[(long)ts * NUNITS + t];
    for (int i = 0; i < NUNITS; ++i) a += hb[i] * W3[i * NUNITS + t];
    __syncthreads();
    ha[t] = fmaxf(a, 0.0f);
    __syncthreads();

    if (t < D) {
        float acc = b4[t];
        for (int i = 0; i < NUNITS; ++i) acc += ha[i] * W4[i * D + t];
        out[(long)b * 17 + 1 + t] = acc;
    }

    // ======== fusion head (threads < 64 active; barriers hit by all) ========
    if (t < 64) {
        const float4* ip = (const float4*)(item + ((long)b * S + t) * D);
        float4 r0 = ip[0], r1 = ip[1], r2 = ip[2], r3 = ip[3];
        sm[t][0]=r0.x;  sm[t][1]=r0.y;  sm[t][2]=r0.z;  sm[t][3]=r0.w;
        sm[t][4]=r1.x;  sm[t][5]=r1.y;  sm[t][6]=r1.z;  sm[t][7]=r1.w;
        sm[t][8]=r2.x;  sm[t][9]=r2.y;  sm[t][10]=r2.z; sm[t][11]=r2.w;
        sm[t][12]=r3.x; sm[t][13]=r3.y; sm[t][14]=r3.z; sm[t][15]=r3.w;
    }
    __syncthreads();

    if (t < D) {
        float sv = 0.0f, mv = -1e30f;
        for (int ss = 0; ss < S; ++ss) {
            float x = sm[ss][t];
            sv += x;
            mv = fmaxf(mv, x);
        }
        fus[t] = fmaxf(sv, 0.0f);
        fus[D + t] = fmaxf(mv, 0.0f);
    }
    __syncthreads();

    if (t < 64) {
        float acc = fc1_b[t];
#pragma unroll
        for (int i = 0; i < 2 * D; ++i) acc += fus[i] * fc1_W[i * 64 + t];
        hid[t] = fmaxf(acc, 0.0f);
    }
    __syncthreads();

    if (t < D) {
        float f = fc2_b[t];
#pragma unroll
        for (int i = 0; i < 64; ++i) f += hid[i] * fc2_W[i * D + t];
        feat_s[t] = fmaxf(f, 0.0f);
    }
    __syncthreads();

    if (t < D) {
        float g = feat_s[t] * ent_emb[(long)v[b] * D + t];
        g += __shfl_xor(g, 1);
        g += __shfl_xor(g, 2);
        g += __shfl_xor(g, 4);
        g += __shfl_xor(g, 8);
        if (t == 0) out[(long)b * 17] = 1.0f / (1.0f + expf(-g));
    }
}

// ---------------------------------------------------------------------------
extern "C" void kernel_launch(void* const* d_in, const int* in_sizes, int n_in,
                              void* d_out, int out_size, void* d_ws, size_t ws_size,
                              hipStream_t stream) {
    const float* usr_emb = (const float*)d_in[0];
    const float* ent_emb = (const float*)d_in[1];
    const float* rel_emb = (const float*)d_in[2];
    const float* agg_W   = (const float*)d_in[3];
    const float* agg_b   = (const float*)d_in[4];
    const float* fc1_W   = (const float*)d_in[5];
    const float* fc1_b   = (const float*)d_in[6];
    const float* fc2_W   = (const float*)d_in[7];
    const float* fc2_b   = (const float*)d_in[8];
    const float* mlp_W1  = (const float*)d_in[9];
    const float* mlp_b1  = (const float*)d_in[10];
    const float* mlp_W2  = (const float*)d_in[11];
    const float* mlp_b2  = (const float*)d_in[12];
    const float* mlp_W3  = (const float*)d_in[13];
    const float* mlp_b3  = (const float*)d_in[14];
    const float* mlp_W4  = (const float*)d_in[15];
    const float* mlp_b4  = (const float*)d_in[16];
    const float* se1     = (const float*)d_in[17];
    const float* se2     = (const float*)d_in[18];
    const float* se3     = (const float*)d_in[19];
    const float* noise_e = (const float*)d_in[20];
    const int* u         = (const int*)d_in[21];
    const int* v         = (const int*)d_in[22];
    const int* click_seq = (const int*)d_in[23];
    const int* adj_ent   = (const int*)d_in[24];
    const int* adj_rel   = (const int*)d_in[25];
    const int* t         = (const int*)d_in[26];
    float* out = (float*)d_out;

    float* ws = (float*)d_ws;
    float* w_tab = ws;                         // B*NR floats
    float* sa    = w_tab + B * NR;             // 128 floats (NSTEPS used)
    float* so    = sa + 128;                   // 128 floats
    float* item  = so + 128;                   // B*S*D floats
    int*   e1s   = (int*)(item + B * S * D);   // B*S*K ints
    int*   r0s   = e1s + B * S * K;            // B*S*K ints

    k_prep_all<<<B, 256, 0, stream>>>(usr_emb, rel_emb, u, click_seq, adj_ent, adj_rel,
                                      w_tab, e1s, r0s, sa, so);
    k_kgcn<<<(B * S) / 4, 256, 0, stream>>>(ent_emb, w_tab, click_seq, adj_ent, adj_rel,
                                            e1s, r0s, agg_W, agg_b, item);
    k_tail<<<B, 128, 0, stream>>>(item, fc1_W, fc1_b, fc2_W, fc2_b, ent_emb, v,
                                  usr_emb, noise_e, u, t, mlp_W1, mlp_b1, mlp_W2, mlp_b2,
                                  mlp_W3, mlp_b3, mlp_W4, mlp_b4, se1, se2, se3, sa, so, out);
}